// Round 8
// baseline (641.457 us; speedup 1.0000x reference)
//
#include <hip/hip_runtime.h>
#include <hip/hip_bf16.h>
#include <math.h>

typedef __hip_bfloat16 bf16;

#define N_NODES 100000
#define HID 128
#define NEG 0.2f
#define NBUCK 256
#define BSHIFT 9          // 512 nodes per bucket
#define ECAP 96           // per-wave LDS edge cache (mean deg 16)

__device__ __forceinline__ float b2f(bf16 x) { return __bfloat162float(x); }
__device__ __forceinline__ bf16 f2b(float x) { return __float2bfloat16(x); }
__device__ __forceinline__ float lo_bf(unsigned int u) {
    union { unsigned int i; float f; } c; c.i = u << 16; return c.f;
}
__device__ __forceinline__ float hi_bf(unsigned int u) {
    union { unsigned int i; float f; } c; c.i = u & 0xffff0000u; return c.f;
}

// ---------------- CSR build: bucketed counting sort ----------------

__global__ void k_zero_int(int* p, int n) {
    int i = blockIdx.x * blockDim.x + threadIdx.x;
    if (i < n) p[i] = 0;
}

__global__ void k_bhist(const int* __restrict__ ei, int E, int* __restrict__ bcnt) {
    __shared__ int h[NBUCK];
    int t = threadIdx.x;
    h[t] = 0;
    __syncthreads();
    int i = blockIdx.x * blockDim.x + t;
    int stride = gridDim.x * blockDim.x;
    for (; i < E; i += stride) {
        int u = ei[i], v = ei[E + i];
        atomicAdd(&h[v >> BSHIFT], 1);
        atomicAdd(&h[u >> BSHIFT], 1);
    }
    __syncthreads();
    if (h[t]) atomicAdd(&bcnt[t], h[t]);
}

__global__ void k_bscan(const int* __restrict__ bcnt, int* __restrict__ bbase,
                        int* __restrict__ bnext) {
    __shared__ int buf[2][NBUCK];
    int t = threadIdx.x;
    int v = bcnt[t];
    buf[0][t] = v;
    __syncthreads();
    int cur = 0;
    for (int off = 1; off < NBUCK; off <<= 1) {
        int x = buf[cur][t] + ((t >= off) ? buf[cur][t - off] : 0);
        buf[cur ^ 1][t] = x;
        cur ^= 1;
        __syncthreads();
    }
    int incl = buf[cur][t];
    int excl = incl - v;
    bbase[t] = excl;
    bnext[t] = excl;
    if (t == NBUCK - 1) bbase[NBUCK] = incl;
}

#define SCH 2048
#define SK 8
__global__ __launch_bounds__(256) void k_bscatter(const int* __restrict__ ei, int E,
                                                  int* __restrict__ bnext,
                                                  int2* __restrict__ pairs) {
    __shared__ int h[NBUCK], base[NBUCK], h2[NBUCK];
    int t = threadIdx.x;
    h[t] = 0; h2[t] = 0;
    __syncthreads();
    int b0 = blockIdx.x * SCH;
    int eu[SK], ev[SK];
#pragma unroll
    for (int k = 0; k < SK; k++) {
        int i = b0 + k * 256 + t;
        if (i < E) {
            int u = ei[i], v = ei[E + i];
            eu[k] = u; ev[k] = v;
            atomicAdd(&h[v >> BSHIFT], 1);
            atomicAdd(&h[u >> BSHIFT], 1);
        } else { eu[k] = -1; ev[k] = -1; }
    }
    __syncthreads();
    if (h[t] > 0) base[t] = atomicAdd(&bnext[t], h[t]);
    __syncthreads();
#pragma unroll
    for (int k = 0; k < SK; k++) {
        if (eu[k] >= 0) {
            int u = eu[k], v = ev[k];
            int bv = v >> BSHIFT;
            pairs[base[bv] + atomicAdd(&h2[bv], 1)] = make_int2(v, u);
            int bu = u >> BSHIFT;
            pairs[base[bu] + atomicAdd(&h2[bu], 1)] = make_int2(u, v);
        }
    }
}

__global__ __launch_bounds__(256) void k_bbuild(const int2* __restrict__ pairs,
                                                const int* __restrict__ bbase,
                                                int* __restrict__ rowptr,
                                                int* __restrict__ col, int n) {
    __shared__ int deg[512];
    __shared__ int off[512];
    __shared__ int s2[2][256];
    int t = threadIdx.x;
    int b = blockIdx.x;
    int node0 = b << BSHIFT;
    deg[t] = 0; deg[t + 256] = 0;
    __syncthreads();
    int p0 = bbase[b], p1 = bbase[b + 1];
    for (int i = p0 + t; i < p1; i += 256) atomicAdd(&deg[pairs[i].x - node0], 1);
    __syncthreads();
    int a0 = deg[2 * t], a1 = deg[2 * t + 1];
    int s = a0 + a1;
    s2[0][t] = s;
    __syncthreads();
    int cur = 0;
    for (int o = 1; o < 256; o <<= 1) {
        int x = s2[cur][t] + ((t >= o) ? s2[cur][t - o] : 0);
        s2[cur ^ 1][t] = x;
        cur ^= 1;
        __syncthreads();
    }
    int excl = s2[cur][t] - s;
    off[2 * t] = excl;
    off[2 * t + 1] = excl + a0;
    __syncthreads();
    for (int j = t; j < 512; j += 256) {
        int node = node0 + j;
        if (node <= n) rowptr[node] = p0 + off[j];
    }
    deg[t] = 0; deg[t + 256] = 0;
    __syncthreads();
    for (int i = p0 + t; i < p1; i += 256) {
        int2 pr = pairs[i];
        int d = pr.x - node0;
        int ofs = atomicAdd(&deg[d], 1);
        col[p0 + off[d] + ofs] = pr.y;
    }
}

// ---------------- Layer 0: z = x @ W0 (fp32 out) + fused es/ed ----------------

__global__ void k_feat0(const float* __restrict__ x, const float* __restrict__ W,
                        const float* __restrict__ as_, const float* __restrict__ ad_,
                        float* __restrict__ z, float* __restrict__ es, float* __restrict__ ed,
                        int n, int indim) {
    int wid = (int)((blockIdx.x * (size_t)blockDim.x + threadIdx.x) >> 6);
    int lane = threadIdx.x & 63;
    if (wid >= n) return;
    const float* xr = x + (size_t)wid * indim;
    float a0 = 0.f, a1 = 0.f;
    for (int k = 0; k < indim; k++) {
        float xv = xr[k];               // wave-uniform
        a0 += xv * W[k * HID + lane];
        a1 += xv * W[k * HID + lane + 64];
    }
    z[(size_t)wid * HID + lane] = a0;
    z[(size_t)wid * HID + lane + 64] = a1;
    float ps = a0 * as_[lane] + a1 * as_[lane + 64];
    float pd = a0 * ad_[lane] + a1 * ad_[lane + 64];
#pragma unroll
    for (int off = 32; off > 0; off >>= 1) {
        ps += __shfl_down(ps, off);
        pd += __shfl_down(pd, off);
    }
    if (lane == 0) { es[wid] = ps; ed[wid] = pd; }
}

// ---------------- Layer 1 feature: z = h @ W1 (fp32 out) + fused es/ed ----------------
// N % 16 == 0 -> no tail guards.

__global__ void k_feat1(const bf16* __restrict__ h, const float* __restrict__ W,
                        const float* __restrict__ as_, const float* __restrict__ ad_,
                        float* __restrict__ z, float* __restrict__ es, float* __restrict__ ed,
                        int n) {
    __shared__ float tile[16][HID];   // 8 KB
    __shared__ float red[2][16][2];
    int c = threadIdx.x;              // 0..127
    int wv = c >> 6, lane = c & 63;
    int n0 = blockIdx.x * 16;
    const uint4* hv = (const uint4*)(h + (size_t)n0 * HID);
#pragma unroll
    for (int q = c; q < 256; q += 128) {
        uint4 raw = hv[q];
        int r = q >> 4, t = q & 15;
        float* dst = &tile[r][t * 8];
        dst[0] = lo_bf(raw.x); dst[1] = hi_bf(raw.x);
        dst[2] = lo_bf(raw.y); dst[3] = hi_bf(raw.y);
        dst[4] = lo_bf(raw.z); dst[5] = hi_bf(raw.z);
        dst[6] = lo_bf(raw.w); dst[7] = hi_bf(raw.w);
    }
    __syncthreads();
    float acc[16];
#pragma unroll
    for (int r = 0; r < 16; r++) acc[r] = 0.f;
    for (int k4 = 0; k4 < HID / 4; k4++) {
        int k = k4 * 4;
        float w0 = W[(k + 0) * HID + c];
        float w1 = W[(k + 1) * HID + c];
        float w2 = W[(k + 2) * HID + c];
        float w3 = W[(k + 3) * HID + c];
#pragma unroll
        for (int r = 0; r < 16; r++) {
            float4 h4 = *(const float4*)&tile[r][k];
            acc[r] += h4.x * w0 + h4.y * w1 + h4.z * w2 + h4.w * w3;
        }
    }
#pragma unroll
    for (int r = 0; r < 16; r++) z[(size_t)(n0 + r) * HID + c] = acc[r];
    // fused es/ed: reduce acc[r]*as/ad over 128 channels (2 waves)
    float asv = as_[c], adv = ad_[c];
#pragma unroll
    for (int r = 0; r < 16; r++) {
        float pe = acc[r] * asv;
        float pd = acc[r] * adv;
#pragma unroll
        for (int off = 32; off > 0; off >>= 1) {
            pe += __shfl_down(pe, off);
            pd += __shfl_down(pd, off);
        }
        if (lane == 0) { red[wv][r][0] = pe; red[wv][r][1] = pd; }
    }
    __syncthreads();
    if (c < 16) es[n0 + c] = red[0][c][0] + red[1][c][0];
    else if (c < 32) ed[n0 + c - 16] = red[0][c - 16][1] + red[1][c - 16][1];
}

// ---------------- Attention aggregation (one wave per dst; fp32 z; LDS logit cache) ----------------

__global__ __launch_bounds__(256) void k_agg(const float* __restrict__ z,
                      const int* __restrict__ rowptr, const int* __restrict__ col,
                      const float* __restrict__ es, const float* __restrict__ ed,
                      const float* __restrict__ bias, bf16* __restrict__ hout, int n) {
    __shared__ float acache[4][ECAP];
    __shared__ int scache[4][ECAP];
    int wv = threadIdx.x >> 6;
    int lane = threadIdx.x & 63;
    int wid = blockIdx.x * 4 + wv;     // N % 4 == 0 -> all waves valid
    if (wid >= n) return;
    int d = wid;
    int s0 = rowptr[d], s1 = rowptr[d + 1];
    float edv = ed[d];
    float aself = es[d] + edv;
    aself = aself > 0.f ? aself : NEG * aself;
    // pass A: max over logits + cache (logit, src)
    float m = aself;
    for (int e = s0 + lane; e < s1; e += 64) {
        int s = col[e];
        float a = es[s] + edv;
        a = a > 0.f ? a : NEG * a;
        int q = e - s0;
        if (q < ECAP) { acache[wv][q] = a; scache[wv][q] = s; }
        m = fmaxf(m, a);
    }
#pragma unroll
    for (int off = 32; off > 0; off >>= 1) m = fmaxf(m, __shfl_xor(m, off));
    __syncthreads();
    // pass B: lane = (g,t); edge slot g in [0,4), channel octet t in [0,16)
    int g = lane >> 4, t = lane & 15;
    const float4* zr = (const float4*)z;   // row = 32 float4
    float acc[8];
#pragma unroll
    for (int j = 0; j < 8; j++) acc[j] = 0.f;
    float den = 0.f;
    for (int e0 = s0; e0 < s1; e0 += 4) {
        int e = e0 + g;
        bool ok = (e < s1);
        int ee = ok ? e : s1 - 1;
        int q = ee - s0;
        int s; float a;
        if (q < ECAP) { s = scache[wv][q]; a = acache[wv][q]; }
        else { s = col[ee]; a = es[s] + edv; a = a > 0.f ? a : NEG * a; }
        float p = ok ? __expf(a - m) : 0.f;
        den += p;
        float4 ra = zr[(size_t)s * 32 + 2 * t];
        float4 rb = zr[(size_t)s * 32 + 2 * t + 1];
        acc[0] += p * ra.x; acc[1] += p * ra.y; acc[2] += p * ra.z; acc[3] += p * ra.w;
        acc[4] += p * rb.x; acc[5] += p * rb.y; acc[6] += p * rb.z; acc[7] += p * rb.w;
    }
#pragma unroll
    for (int off = 16; off <= 32; off <<= 1) {
        den += __shfl_xor(den, off);
#pragma unroll
        for (int j = 0; j < 8; j++) acc[j] += __shfl_xor(acc[j], off);
    }
    if (g == 0) {
        float pself = __expf(aself - m);
        den += pself;
        float4 ra = zr[(size_t)d * 32 + 2 * t];
        float4 rb = zr[(size_t)d * 32 + 2 * t + 1];
        acc[0] += pself * ra.x; acc[1] += pself * ra.y;
        acc[2] += pself * ra.z; acc[3] += pself * ra.w;
        acc[4] += pself * rb.x; acc[5] += pself * rb.y;
        acc[6] += pself * rb.z; acc[7] += pself * rb.w;
        float inv = 1.f / den;
        union { bf16 hv[8]; uint4 v; } uo;
#pragma unroll
        for (int j = 0; j < 8; j++) {
            float o = acc[j] * inv + bias[t * 8 + j];
            o = o > 0.f ? o : expm1f(o);
            uo.hv[j] = f2b(o);
        }
        ((uint4*)hout)[(size_t)d * 16 + t] = uo.v;
    }
}

// ---------------- Fused actor MLP + softmax: one wave per group of 16 candidates ----------------

__global__ void k_group(const bf16* __restrict__ h, const int* __restrict__ cand,
                        const float* __restrict__ mW0, const float* __restrict__ mb0,
                        const float* __restrict__ mW1, const float* __restrict__ mb1,
                        float* __restrict__ out) {
    __shared__ float tile[16][HID];
    __shared__ int cidx[16];
    __shared__ float sc[16];
    int lane = threadIdx.x;       // 0..63 (one wave)
    int g = blockIdx.x;
    if (lane < 16) cidx[lane] = cand[g * 16 + lane];
    __syncthreads();
#pragma unroll
    for (int q = lane; q < 256; q += 64) {
        int r = q >> 4, t = q & 15;
        uint4 raw = ((const uint4*)(h + (size_t)cidx[r] * HID))[t];
        float* dst = &tile[r][t * 8];
        dst[0] = lo_bf(raw.x); dst[1] = hi_bf(raw.x);
        dst[2] = lo_bf(raw.y); dst[3] = hi_bf(raw.y);
        dst[4] = lo_bf(raw.z); dst[5] = hi_bf(raw.z);
        dst[6] = lo_bf(raw.w); dst[7] = hi_bf(raw.w);
    }
    __syncthreads();
    float acc0[16], acc1[16];
#pragma unroll
    for (int r = 0; r < 16; r++) { acc0[r] = 0.f; acc1[r] = 0.f; }
    for (int k4 = 0; k4 < HID / 4; k4++) {
        int k = k4 * 4;
        float wa0 = mW0[(k + 0) * HID + lane], wb0 = mW0[(k + 0) * HID + lane + 64];
        float wa1 = mW0[(k + 1) * HID + lane], wb1 = mW0[(k + 1) * HID + lane + 64];
        float wa2 = mW0[(k + 2) * HID + lane], wb2 = mW0[(k + 2) * HID + lane + 64];
        float wa3 = mW0[(k + 3) * HID + lane], wb3 = mW0[(k + 3) * HID + lane + 64];
#pragma unroll
        for (int r = 0; r < 16; r++) {
            float4 h4 = *(const float4*)&tile[r][k];
            acc0[r] += h4.x * wa0 + h4.y * wa1 + h4.z * wa2 + h4.w * wa3;
            acc1[r] += h4.x * wb0 + h4.y * wb1 + h4.z * wb2 + h4.w * wb3;
        }
    }
    float w1a = mW1[lane], w1b = mW1[lane + 64];
    float b0a = mb0[lane], b0b = mb0[lane + 64];
    float bias1 = mb1[0];
#pragma unroll
    for (int r = 0; r < 16; r++) {
        float s = fmaxf(acc0[r] + b0a, 0.f) * w1a + fmaxf(acc1[r] + b0b, 0.f) * w1b;
#pragma unroll
        for (int off = 32; off > 0; off >>= 1) s += __shfl_down(s, off);
        if (lane == 0) sc[r] = s + bias1;
    }
    __syncthreads();
    if (lane == 0) {
        float m = -1e30f;
#pragma unroll
        for (int j = 0; j < 16; j++) m = fmaxf(m, sc[j]);
        float e[16], den = 0.f;
#pragma unroll
        for (int j = 0; j < 16; j++) { e[j] = __expf(sc[j] - m); den += e[j]; }
        float inv = 1.f / den;
#pragma unroll
        for (int j = 0; j < 16; j++) out[g * 16 + j] = e[j] * inv;
    }
}

// ---------------- launch ----------------

extern "C" void kernel_launch(void* const* d_in, const int* in_sizes, int n_in,
                              void* d_out, int out_size, void* d_ws, size_t ws_size,
                              hipStream_t stream) {
    const int N = N_NODES;
    const float* state = (const float*)d_in[0];
    const int* ei   = (const int*)d_in[1];
    const int* cand = (const int*)d_in[2];
    const float* W0  = (const float*)d_in[3];
    const float* as0 = (const float*)d_in[4];
    const float* ad0 = (const float*)d_in[5];
    const float* b0  = (const float*)d_in[6];
    const float* W1  = (const float*)d_in[7];
    const float* as1 = (const float*)d_in[8];
    const float* ad1 = (const float*)d_in[9];
    const float* b1  = (const float*)d_in[10];
    const float* mW0 = (const float*)d_in[11];
    const float* mb0 = (const float*)d_in[12];
    const float* mW1 = (const float*)d_in[13];
    const float* mb1 = (const float*)d_in[14];

    int E = in_sizes[1] / 2;
    int M = 2 * E;                    // symmetrized; self-loops inline in k_agg
    int indim = in_sizes[0] / N;
    int ncand = in_sizes[2];          // 65536
    int ngroups = ncand / 16;         // 4096

    // workspace (~85 MB; ws >= 111 MB evidenced by R2's working scores buffer at 110.8 MB)
    char* p = (char*)d_ws;
    float* zf = (float*)p;            p += (size_t)N * HID * 4;   // 51.2 MB fp32 z
    bf16* hb  = (bf16*)p;             p += (size_t)N * HID * 2;   // 25.6 MB bf16 h
    float* es = (float*)p;            p += (size_t)N * 4;
    float* ed = (float*)p;            p += (size_t)N * 4;
    int* rowptr = (int*)p;            p += (size_t)(N + 1) * 4;
    int* col    = (int*)p;            p += (size_t)M * 4;         // 6.4 MB
    int* bcnt   = (int*)p;            p += (NBUCK + 1) * 4;
    int* bbase  = (int*)p;            p += (NBUCK + 1) * 4;
    int* bnext  = (int*)p;            p += NBUCK * 4;
    int2* pairs = (int2*)zf;          // 12.8 MB overlay (zf dead until k_feat0)

    int nwb = N / 4;                  // one-wave-per-node kernels, 256 thr

    // ---- CSR build (bucketed counting sort) ----
    k_zero_int<<<1, 256, 0, stream>>>(bcnt, NBUCK);
    k_bhist<<<512, 256, 0, stream>>>(ei, E, bcnt);
    k_bscan<<<1, NBUCK, 0, stream>>>(bcnt, bbase, bnext);
    k_bscatter<<<(E + SCH - 1) / SCH, 256, 0, stream>>>(ei, E, bnext, pairs);
    k_bbuild<<<NBUCK, 256, 0, stream>>>(pairs, bbase, rowptr, col, N);

    // ---- GAT layer 0 ----
    k_feat0<<<nwb, 256, 0, stream>>>(state, W0, as0, ad0, zf, es, ed, N, indim);
    k_agg<<<nwb, 256, 0, stream>>>(zf, rowptr, col, es, ed, b0, hb, N);

    // ---- GAT layer 1 (es/ed fused into feat1) ----
    k_feat1<<<N / 16, HID, 0, stream>>>(hb, W1, as1, ad1, zf, es, ed, N);
    k_agg<<<nwb, 256, 0, stream>>>(zf, rowptr, col, es, ed, b1, hb, N);

    // ---- fused actor MLP + softmax ----
    k_group<<<ngroups, 64, 0, stream>>>(hb, cand, mW0, mb0, mW1, mb1, (float*)d_out);
}

// Round 9
// 490.883 us; speedup vs baseline: 1.3067x; 1.3067x over previous
//
#include <hip/hip_runtime.h>
#include <hip/hip_bf16.h>
#include <math.h>

typedef __hip_bfloat16 bf16;

#define N_NODES 100000
#define HID 128
#define NEG 0.2f
#define NBUCK 256
#define BSHIFT 9          // 512 nodes per bucket
#define ECAP 96           // per-wave LDS edge cache (mean deg 16)

__device__ __forceinline__ float b2f(bf16 x) { return __bfloat162float(x); }
__device__ __forceinline__ bf16 f2b(float x) { return __float2bfloat16(x); }
__device__ __forceinline__ float lo_bf(unsigned int u) {
    union { unsigned int i; float f; } c; c.i = u << 16; return c.f;
}
__device__ __forceinline__ float hi_bf(unsigned int u) {
    union { unsigned int i; float f; } c; c.i = u & 0xffff0000u; return c.f;
}

// ---------------- CSR build: bucketed counting sort ----------------

__global__ void k_zero_int(int* p, int n) {
    int i = blockIdx.x * blockDim.x + threadIdx.x;
    if (i < n) p[i] = 0;
}

__global__ void k_bhist(const int* __restrict__ ei, int E, int* __restrict__ bcnt) {
    __shared__ int h[NBUCK];
    int t = threadIdx.x;
    h[t] = 0;
    __syncthreads();
    int i = blockIdx.x * blockDim.x + t;
    int stride = gridDim.x * blockDim.x;
    for (; i < E; i += stride) {
        int u = ei[i], v = ei[E + i];
        atomicAdd(&h[v >> BSHIFT], 1);
        atomicAdd(&h[u >> BSHIFT], 1);
    }
    __syncthreads();
    if (h[t]) atomicAdd(&bcnt[t], h[t]);
}

__global__ void k_bscan(const int* __restrict__ bcnt, int* __restrict__ bbase,
                        int* __restrict__ bnext) {
    __shared__ int buf[2][NBUCK];
    int t = threadIdx.x;
    int v = bcnt[t];
    buf[0][t] = v;
    __syncthreads();
    int cur = 0;
    for (int off = 1; off < NBUCK; off <<= 1) {
        int x = buf[cur][t] + ((t >= off) ? buf[cur][t - off] : 0);
        buf[cur ^ 1][t] = x;
        cur ^= 1;
        __syncthreads();
    }
    int incl = buf[cur][t];
    int excl = incl - v;
    bbase[t] = excl;
    bnext[t] = excl;
    if (t == NBUCK - 1) bbase[NBUCK] = incl;
}

#define SCH 2048
#define SK 8
__global__ __launch_bounds__(256) void k_bscatter(const int* __restrict__ ei, int E,
                                                  int* __restrict__ bnext,
                                                  int2* __restrict__ pairs) {
    __shared__ int h[NBUCK], base[NBUCK], h2[NBUCK];
    int t = threadIdx.x;
    h[t] = 0; h2[t] = 0;
    __syncthreads();
    int b0 = blockIdx.x * SCH;
    int eu[SK], ev[SK];
#pragma unroll
    for (int k = 0; k < SK; k++) {
        int i = b0 + k * 256 + t;
        if (i < E) {
            int u = ei[i], v = ei[E + i];
            eu[k] = u; ev[k] = v;
            atomicAdd(&h[v >> BSHIFT], 1);
            atomicAdd(&h[u >> BSHIFT], 1);
        } else { eu[k] = -1; ev[k] = -1; }
    }
    __syncthreads();
    if (h[t] > 0) base[t] = atomicAdd(&bnext[t], h[t]);
    __syncthreads();
#pragma unroll
    for (int k = 0; k < SK; k++) {
        if (eu[k] >= 0) {
            int u = eu[k], v = ev[k];
            int bv = v >> BSHIFT;
            pairs[base[bv] + atomicAdd(&h2[bv], 1)] = make_int2(v, u);
            int bu = u >> BSHIFT;
            pairs[base[bu] + atomicAdd(&h2[bu], 1)] = make_int2(u, v);
        }
    }
}

__global__ __launch_bounds__(256) void k_bbuild(const int2* __restrict__ pairs,
                                                const int* __restrict__ bbase,
                                                int* __restrict__ rowptr,
                                                int* __restrict__ col, int n) {
    __shared__ int deg[512];
    __shared__ int off[512];
    __shared__ int s2[2][256];
    int t = threadIdx.x;
    int b = blockIdx.x;
    int node0 = b << BSHIFT;
    deg[t] = 0; deg[t + 256] = 0;
    __syncthreads();
    int p0 = bbase[b], p1 = bbase[b + 1];
    for (int i = p0 + t; i < p1; i += 256) atomicAdd(&deg[pairs[i].x - node0], 1);
    __syncthreads();
    int a0 = deg[2 * t], a1 = deg[2 * t + 1];
    int s = a0 + a1;
    s2[0][t] = s;
    __syncthreads();
    int cur = 0;
    for (int o = 1; o < 256; o <<= 1) {
        int x = s2[cur][t] + ((t >= o) ? s2[cur][t - o] : 0);
        s2[cur ^ 1][t] = x;
        cur ^= 1;
        __syncthreads();
    }
    int excl = s2[cur][t] - s;
    off[2 * t] = excl;
    off[2 * t + 1] = excl + a0;
    __syncthreads();
    for (int j = t; j < 512; j += 256) {
        int node = node0 + j;
        if (node <= n) rowptr[node] = p0 + off[j];
    }
    deg[t] = 0; deg[t + 256] = 0;
    __syncthreads();
    for (int i = p0 + t; i < p1; i += 256) {
        int2 pr = pairs[i];
        int d = pr.x - node0;
        int ofs = atomicAdd(&deg[d], 1);
        col[p0 + off[d] + ofs] = pr.y;
    }
}

// ---------------- Layer 0: z = x @ W0 (bf16 out) + fused es/ed ----------------

__global__ void k_feat0(const float* __restrict__ x, const float* __restrict__ W,
                        const float* __restrict__ as_, const float* __restrict__ ad_,
                        bf16* __restrict__ z, float* __restrict__ es, float* __restrict__ ed,
                        int n, int indim) {
    int wid = (int)((blockIdx.x * (size_t)blockDim.x + threadIdx.x) >> 6);
    int lane = threadIdx.x & 63;
    if (wid >= n) return;
    const float* xr = x + (size_t)wid * indim;
    float a0 = 0.f, a1 = 0.f;
    for (int k = 0; k < indim; k++) {
        float xv = xr[k];               // wave-uniform
        a0 += xv * W[k * HID + lane];
        a1 += xv * W[k * HID + lane + 64];
    }
    z[(size_t)wid * HID + lane] = f2b(a0);
    z[(size_t)wid * HID + lane + 64] = f2b(a1);
    float ps = a0 * as_[lane] + a1 * as_[lane + 64];
    float pd = a0 * ad_[lane] + a1 * ad_[lane + 64];
#pragma unroll
    for (int off = 32; off > 0; off >>= 1) {
        ps += __shfl_down(ps, off);
        pd += __shfl_down(pd, off);
    }
    if (lane == 0) { es[wid] = ps; ed[wid] = pd; }
}

// ---------------- Layer 1 feature: z = h @ W1 (bf16 out) + fused es/ed ----------------
// N % 16 == 0 -> no tail guards.

__global__ void k_feat1(const bf16* __restrict__ h, const float* __restrict__ W,
                        const float* __restrict__ as_, const float* __restrict__ ad_,
                        bf16* __restrict__ z, float* __restrict__ es, float* __restrict__ ed,
                        int n) {
    __shared__ float tile[16][HID];   // 8 KB
    __shared__ float red[2][16][2];
    int c = threadIdx.x;              // 0..127
    int wv = c >> 6, lane = c & 63;
    int n0 = blockIdx.x * 16;
    const uint4* hv = (const uint4*)(h + (size_t)n0 * HID);
#pragma unroll
    for (int q = c; q < 256; q += 128) {
        uint4 raw = hv[q];
        int r = q >> 4, t = q & 15;
        float* dst = &tile[r][t * 8];
        dst[0] = lo_bf(raw.x); dst[1] = hi_bf(raw.x);
        dst[2] = lo_bf(raw.y); dst[3] = hi_bf(raw.y);
        dst[4] = lo_bf(raw.z); dst[5] = hi_bf(raw.z);
        dst[6] = lo_bf(raw.w); dst[7] = hi_bf(raw.w);
    }
    __syncthreads();
    float acc[16];
#pragma unroll
    for (int r = 0; r < 16; r++) acc[r] = 0.f;
    for (int k4 = 0; k4 < HID / 4; k4++) {
        int k = k4 * 4;
        float w0 = W[(k + 0) * HID + c];
        float w1 = W[(k + 1) * HID + c];
        float w2 = W[(k + 2) * HID + c];
        float w3 = W[(k + 3) * HID + c];
#pragma unroll
        for (int r = 0; r < 16; r++) {
            float4 h4 = *(const float4*)&tile[r][k];
            acc[r] += h4.x * w0 + h4.y * w1 + h4.z * w2 + h4.w * w3;
        }
    }
#pragma unroll
    for (int r = 0; r < 16; r++) z[(size_t)(n0 + r) * HID + c] = f2b(acc[r]);
    // fused es/ed
    float asv = as_[c], adv = ad_[c];
#pragma unroll
    for (int r = 0; r < 16; r++) {
        float pe = acc[r] * asv;
        float pd = acc[r] * adv;
#pragma unroll
        for (int off = 32; off > 0; off >>= 1) {
            pe += __shfl_down(pe, off);
            pd += __shfl_down(pd, off);
        }
        if (lane == 0) { red[wv][r][0] = pe; red[wv][r][1] = pd; }
    }
    __syncthreads();
    if (c < 16) es[n0 + c] = red[0][c][0] + red[1][c][0];
    else if (c < 32) ed[n0 + c - 16] = red[0][c - 16][1] + red[1][c - 16][1];
}

// ---------------- Attention aggregation (bf16 z; per-wave LDS logit cache) ----------------

__global__ __launch_bounds__(256) void k_agg(const bf16* __restrict__ z,
                      const int* __restrict__ rowptr, const int* __restrict__ col,
                      const float* __restrict__ es, const float* __restrict__ ed,
                      const float* __restrict__ bias, bf16* __restrict__ hout, int n) {
    __shared__ float acache[4][ECAP];
    __shared__ int scache[4][ECAP];
    int wv = threadIdx.x >> 6;
    int lane = threadIdx.x & 63;
    int wid = blockIdx.x * 4 + wv;     // N % 4 == 0 -> all waves valid
    if (wid >= n) return;
    int d = wid;
    int s0 = rowptr[d], s1 = rowptr[d + 1];
    float edv = ed[d];
    float aself = es[d] + edv;
    aself = aself > 0.f ? aself : NEG * aself;
    // pass A: max over logits + per-wave cache (no block barrier needed: same-wave RAW)
    float m = aself;
    for (int e = s0 + lane; e < s1; e += 64) {
        int s = col[e];
        float a = es[s] + edv;
        a = a > 0.f ? a : NEG * a;
        int q = e - s0;
        if (q < ECAP) { acache[wv][q] = a; scache[wv][q] = s; }
        m = fmaxf(m, a);
    }
#pragma unroll
    for (int off = 32; off > 0; off >>= 1) m = fmaxf(m, __shfl_xor(m, off));
    // pass B: lane = (g,t); edge slot g in [0,4), channel octet t in [0,16)
    int g = lane >> 4, t = lane & 15;
    const uint4* zr = (const uint4*)z;   // row = 16 uint4 (128 bf16)
    float acc[8];
#pragma unroll
    for (int j = 0; j < 8; j++) acc[j] = 0.f;
    float den = 0.f;
    for (int e0 = s0; e0 < s1; e0 += 4) {
        int e = e0 + g;
        bool ok = (e < s1);
        int ee = ok ? e : s1 - 1;
        int q = ee - s0;
        int s; float a;
        if (q < ECAP) { s = scache[wv][q]; a = acache[wv][q]; }
        else { s = col[ee]; a = es[s] + edv; a = a > 0.f ? a : NEG * a; }
        float p = ok ? __expf(a - m) : 0.f;
        den += p;
        uint4 raw = zr[(size_t)s * 16 + t];
        acc[0] += p * lo_bf(raw.x); acc[1] += p * hi_bf(raw.x);
        acc[2] += p * lo_bf(raw.y); acc[3] += p * hi_bf(raw.y);
        acc[4] += p * lo_bf(raw.z); acc[5] += p * hi_bf(raw.z);
        acc[6] += p * lo_bf(raw.w); acc[7] += p * hi_bf(raw.w);
    }
#pragma unroll
    for (int off = 16; off <= 32; off <<= 1) {
        den += __shfl_xor(den, off);
#pragma unroll
        for (int j = 0; j < 8; j++) acc[j] += __shfl_xor(acc[j], off);
    }
    if (g == 0) {
        float pself = __expf(aself - m);
        den += pself;
        uint4 raw = zr[(size_t)d * 16 + t];
        acc[0] += pself * lo_bf(raw.x); acc[1] += pself * hi_bf(raw.x);
        acc[2] += pself * lo_bf(raw.y); acc[3] += pself * hi_bf(raw.y);
        acc[4] += pself * lo_bf(raw.z); acc[5] += pself * hi_bf(raw.z);
        acc[6] += pself * lo_bf(raw.w); acc[7] += pself * hi_bf(raw.w);
        float inv = 1.f / den;
        union { bf16 hv[8]; uint4 v; } uo;
#pragma unroll
        for (int j = 0; j < 8; j++) {
            float o = acc[j] * inv + bias[t * 8 + j];
            o = o > 0.f ? o : (__expf(o) - 1.f);   // elu via hw exp
            uo.hv[j] = f2b(o);
        }
        ((uint4*)hout)[(size_t)d * 16 + t] = uo.v;
    }
}

// ---------------- Fused actor MLP + softmax: 4 waves/block, one group per wave ----------------

__global__ __launch_bounds__(256) void k_group(const bf16* __restrict__ h,
                        const int* __restrict__ cand,
                        const float* __restrict__ mW0, const float* __restrict__ mb0,
                        const float* __restrict__ mW1, const float* __restrict__ mb1,
                        float* __restrict__ out) {
    __shared__ float tile[4][16][HID];   // 32 KB
    __shared__ int cidx[4][16];
    __shared__ float sc[4][16];
    int wv = threadIdx.x >> 6;
    int lane = threadIdx.x & 63;
    int g = blockIdx.x * 4 + wv;         // ngroups % 4 == 0
    if (lane < 16) cidx[wv][lane] = cand[g * 16 + lane];
    // same-wave LDS producer/consumer -> no block barrier
#pragma unroll
    for (int q = lane; q < 256; q += 64) {
        int r = q >> 4, t = q & 15;
        uint4 raw = ((const uint4*)(h + (size_t)cidx[wv][r] * HID))[t];
        float* dst = &tile[wv][r][t * 8];
        dst[0] = lo_bf(raw.x); dst[1] = hi_bf(raw.x);
        dst[2] = lo_bf(raw.y); dst[3] = hi_bf(raw.y);
        dst[4] = lo_bf(raw.z); dst[5] = hi_bf(raw.z);
        dst[6] = lo_bf(raw.w); dst[7] = hi_bf(raw.w);
    }
    float acc0[16], acc1[16];
#pragma unroll
    for (int r = 0; r < 16; r++) { acc0[r] = 0.f; acc1[r] = 0.f; }
    for (int k4 = 0; k4 < HID / 4; k4++) {
        int k = k4 * 4;
        float wa0 = mW0[(k + 0) * HID + lane], wb0 = mW0[(k + 0) * HID + lane + 64];
        float wa1 = mW0[(k + 1) * HID + lane], wb1 = mW0[(k + 1) * HID + lane + 64];
        float wa2 = mW0[(k + 2) * HID + lane], wb2 = mW0[(k + 2) * HID + lane + 64];
        float wa3 = mW0[(k + 3) * HID + lane], wb3 = mW0[(k + 3) * HID + lane + 64];
#pragma unroll
        for (int r = 0; r < 16; r++) {
            float4 h4 = *(const float4*)&tile[wv][r][k];
            acc0[r] += h4.x * wa0 + h4.y * wa1 + h4.z * wa2 + h4.w * wa3;
            acc1[r] += h4.x * wb0 + h4.y * wb1 + h4.z * wb2 + h4.w * wb3;
        }
    }
    float w1a = mW1[lane], w1b = mW1[lane + 64];
    float b0a = mb0[lane], b0b = mb0[lane + 64];
    float bias1 = mb1[0];
#pragma unroll
    for (int r = 0; r < 16; r++) {
        float s = fmaxf(acc0[r] + b0a, 0.f) * w1a + fmaxf(acc1[r] + b0b, 0.f) * w1b;
#pragma unroll
        for (int off = 32; off > 0; off >>= 1) s += __shfl_down(s, off);
        if (lane == 0) sc[wv][r] = s + bias1;
    }
    // softmax across lanes 0..15 (same-wave)
    if (lane < 16) {
        float s = sc[wv][lane];
        float m = s;
#pragma unroll
        for (int off = 1; off < 16; off <<= 1) m = fmaxf(m, __shfl_xor(m, off));
        float e = __expf(s - m);
        float den = e;
#pragma unroll
        for (int off = 1; off < 16; off <<= 1) den += __shfl_xor(den, off);
        out[g * 16 + lane] = e / den;
    }
}

// ---------------- launch ----------------

extern "C" void kernel_launch(void* const* d_in, const int* in_sizes, int n_in,
                              void* d_out, int out_size, void* d_ws, size_t ws_size,
                              hipStream_t stream) {
    const int N = N_NODES;
    const float* state = (const float*)d_in[0];
    const int* ei   = (const int*)d_in[1];
    const int* cand = (const int*)d_in[2];
    const float* W0  = (const float*)d_in[3];
    const float* as0 = (const float*)d_in[4];
    const float* ad0 = (const float*)d_in[5];
    const float* b0  = (const float*)d_in[6];
    const float* W1  = (const float*)d_in[7];
    const float* as1 = (const float*)d_in[8];
    const float* ad1 = (const float*)d_in[9];
    const float* b1  = (const float*)d_in[10];
    const float* mW0 = (const float*)d_in[11];
    const float* mb0 = (const float*)d_in[12];
    const float* mW1 = (const float*)d_in[13];
    const float* mb1 = (const float*)d_in[14];

    int E = in_sizes[1] / 2;
    int M = 2 * E;                    // symmetrized; self-loops inline in k_agg
    int indim = in_sizes[0] / N;
    int ncand = in_sizes[2];          // 65536
    int ngroups = ncand / 16;         // 4096

    // workspace (~59 MB); pairs overlays zb (dead until k_feat0)
    char* p = (char*)d_ws;
    bf16* zb = (bf16*)p;              p += (size_t)N * HID * 2;   // 25.6 MB
    bf16* hb = (bf16*)p;              p += (size_t)N * HID * 2;   // 25.6 MB
    float* es = (float*)p;            p += (size_t)N * 4;
    float* ed = (float*)p;            p += (size_t)N * 4;
    int* rowptr = (int*)p;            p += (size_t)(N + 1) * 4;
    int* col    = (int*)p;            p += (size_t)M * 4;         // 6.4 MB
    int* bcnt   = (int*)p;            p += (NBUCK + 1) * 4;
    int* bbase  = (int*)p;            p += (NBUCK + 1) * 4;
    int* bnext  = (int*)p;            p += NBUCK * 4;
    int2* pairs = (int2*)zb;          // 12.8 MB overlay

    int nwb = N / 4;                  // one-wave-per-node kernels, 256 thr

    // ---- CSR build (bucketed counting sort) ----
    k_zero_int<<<1, 256, 0, stream>>>(bcnt, NBUCK);
    k_bhist<<<512, 256, 0, stream>>>(ei, E, bcnt);
    k_bscan<<<1, NBUCK, 0, stream>>>(bcnt, bbase, bnext);
    k_bscatter<<<(E + SCH - 1) / SCH, 256, 0, stream>>>(ei, E, bnext, pairs);
    k_bbuild<<<NBUCK, 256, 0, stream>>>(pairs, bbase, rowptr, col, N);

    // ---- GAT layer 0 ----
    k_feat0<<<nwb, 256, 0, stream>>>(state, W0, as0, ad0, zb, es, ed, N, indim);
    k_agg<<<nwb, 256, 0, stream>>>(zb, rowptr, col, es, ed, b0, hb, N);

    // ---- GAT layer 1 (es/ed fused into feat1) ----
    k_feat1<<<N / 16, HID, 0, stream>>>(hb, W1, as1, ad1, zb, es, ed, N);
    k_agg<<<nwb, 256, 0, stream>>>(zb, rowptr, col, es, ed, b1, hb, N);

    // ---- fused actor MLP + softmax (4 groups per 256-thr block) ----
    k_group<<<ngroups / 4, 256, 0, stream>>>(hb, cand, mW0, mb0, mW1, mb1, (float*)d_out);
}

// Round 10
// 391.577 us; speedup vs baseline: 1.6381x; 1.2536x over previous
//
#include <hip/hip_runtime.h>
#include <hip/hip_bf16.h>
#include <math.h>
#include <stdint.h>

typedef __hip_bfloat16 bf16;
typedef __attribute__((ext_vector_type(8))) short s8v;   // 8 bf16 = 4 VGPR (MFMA A/B frag)
typedef __attribute__((ext_vector_type(4))) float f4v;   // MFMA C/D frag

#define N_NODES 100000
#define HID 128
#define NEG 0.2f
#define NBUCK 256
#define BSHIFT 9          // 512 nodes per bucket
#define ECAP 96           // per-wave LDS edge cache (mean deg 16)

__device__ __forceinline__ float b2f(bf16 x) { return __bfloat162float(x); }
__device__ __forceinline__ bf16 f2b(float x) { return __float2bfloat16(x); }
__device__ __forceinline__ float lo_bf(unsigned int u) {
    union { unsigned int i; float f; } c; c.i = u << 16; return c.f;
}
__device__ __forceinline__ float hi_bf(unsigned int u) {
    union { unsigned int i; float f; } c; c.i = u & 0xffff0000u; return c.f;
}
__device__ __forceinline__ short bfbits(float x) {
    union { bf16 b; short s; } u; u.b = f2b(x); return u.s;
}

// ---------------- CSR build: bucketed counting sort ----------------

__global__ void k_zero_int(int* p, int n) {
    int i = blockIdx.x * blockDim.x + threadIdx.x;
    if (i < n) p[i] = 0;
}

__global__ void k_bhist(const int* __restrict__ ei, int E, int* __restrict__ bcnt) {
    __shared__ int h[NBUCK];
    int t = threadIdx.x;
    h[t] = 0;
    __syncthreads();
    int i = blockIdx.x * blockDim.x + t;
    int stride = gridDim.x * blockDim.x;
    for (; i < E; i += stride) {
        int u = ei[i], v = ei[E + i];
        atomicAdd(&h[v >> BSHIFT], 1);
        atomicAdd(&h[u >> BSHIFT], 1);
    }
    __syncthreads();
    if (h[t]) atomicAdd(&bcnt[t], h[t]);
}

__global__ void k_bscan(const int* __restrict__ bcnt, int* __restrict__ bbase,
                        int* __restrict__ bnext) {
    __shared__ int buf[2][NBUCK];
    int t = threadIdx.x;
    int v = bcnt[t];
    buf[0][t] = v;
    __syncthreads();
    int cur = 0;
    for (int off = 1; off < NBUCK; off <<= 1) {
        int x = buf[cur][t] + ((t >= off) ? buf[cur][t - off] : 0);
        buf[cur ^ 1][t] = x;
        cur ^= 1;
        __syncthreads();
    }
    int incl = buf[cur][t];
    int excl = incl - v;
    bbase[t] = excl;
    bnext[t] = excl;
    if (t == NBUCK - 1) bbase[NBUCK] = incl;
}

#define SCH 2048
#define SK 8
__global__ __launch_bounds__(256) void k_bscatter(const int* __restrict__ ei, int E,
                                                  int* __restrict__ bnext,
                                                  int2* __restrict__ pairs) {
    __shared__ int h[NBUCK], base[NBUCK], h2[NBUCK];
    int t = threadIdx.x;
    h[t] = 0; h2[t] = 0;
    __syncthreads();
    int b0 = blockIdx.x * SCH;
    int eu[SK], ev[SK];
#pragma unroll
    for (int k = 0; k < SK; k++) {
        int i = b0 + k * 256 + t;
        if (i < E) {
            int u = ei[i], v = ei[E + i];
            eu[k] = u; ev[k] = v;
            atomicAdd(&h[v >> BSHIFT], 1);
            atomicAdd(&h[u >> BSHIFT], 1);
        } else { eu[k] = -1; ev[k] = -1; }
    }
    __syncthreads();
    if (h[t] > 0) base[t] = atomicAdd(&bnext[t], h[t]);
    __syncthreads();
#pragma unroll
    for (int k = 0; k < SK; k++) {
        if (eu[k] >= 0) {
            int u = eu[k], v = ev[k];
            int bv = v >> BSHIFT;
            pairs[base[bv] + atomicAdd(&h2[bv], 1)] = make_int2(v, u);
            int bu = u >> BSHIFT;
            pairs[base[bu] + atomicAdd(&h2[bu], 1)] = make_int2(u, v);
        }
    }
}

__global__ __launch_bounds__(256) void k_bbuild(const int2* __restrict__ pairs,
                                                const int* __restrict__ bbase,
                                                int* __restrict__ rowptr,
                                                int* __restrict__ col, int n) {
    __shared__ int deg[512];
    __shared__ int off[512];
    __shared__ int s2[2][256];
    int t = threadIdx.x;
    int b = blockIdx.x;
    int node0 = b << BSHIFT;
    deg[t] = 0; deg[t + 256] = 0;
    __syncthreads();
    int p0 = bbase[b], p1 = bbase[b + 1];
    for (int i = p0 + t; i < p1; i += 256) atomicAdd(&deg[pairs[i].x - node0], 1);
    __syncthreads();
    int a0 = deg[2 * t], a1 = deg[2 * t + 1];
    int s = a0 + a1;
    s2[0][t] = s;
    __syncthreads();
    int cur = 0;
    for (int o = 1; o < 256; o <<= 1) {
        int x = s2[cur][t] + ((t >= o) ? s2[cur][t - o] : 0);
        s2[cur ^ 1][t] = x;
        cur ^= 1;
        __syncthreads();
    }
    int excl = s2[cur][t] - s;
    off[2 * t] = excl;
    off[2 * t + 1] = excl + a0;
    __syncthreads();
    for (int j = t; j < 512; j += 256) {
        int node = node0 + j;
        if (node <= n) rowptr[node] = p0 + off[j];
    }
    deg[t] = 0; deg[t + 256] = 0;
    __syncthreads();
    for (int i = p0 + t; i < p1; i += 256) {
        int2 pr = pairs[i];
        int d = pr.x - node0;
        int ofs = atomicAdd(&deg[d], 1);
        col[p0 + off[d] + ofs] = pr.y;
    }
}

// ---------------- weight pack: fp32 [128][128] -> MFMA B-frag layout, bf16 hi + bf16 residual ----
// frag index = ((kb*8+cb)*64 + lane)*8 + j; B[k= kb*32+(lane>>4)*8+j][c= cb*16+(lane&15)]
// lo half stored at +16384.

__global__ void k_pack(const float* __restrict__ W, short* __restrict__ frag) {
    int idx = blockIdx.x * 256 + threadIdx.x;   // 0..16383
    int j = idx & 7;
    int lane = (idx >> 3) & 63;
    int cb = (idx >> 9) & 7;
    int kb = idx >> 12;
    int k = kb * 32 + (lane >> 4) * 8 + j;
    int c = cb * 16 + (lane & 15);
    float w = W[k * HID + c];
    bf16 hi = f2b(w);
    float rem = w - b2f(hi);
    union { bf16 b; short s; } u;
    u.b = hi;
    frag[idx] = u.s;
    frag[16384 + idx] = bfbits(rem);
}

// ---------------- Layer 0: z = x @ W0 (bf16 out) + fused es/ed ----------------

__global__ void k_feat0(const float* __restrict__ x, const float* __restrict__ W,
                        const float* __restrict__ as_, const float* __restrict__ ad_,
                        bf16* __restrict__ z, float* __restrict__ es, float* __restrict__ ed,
                        int n, int indim) {
    int wid = (int)((blockIdx.x * (size_t)blockDim.x + threadIdx.x) >> 6);
    int lane = threadIdx.x & 63;
    if (wid >= n) return;
    const float* xr = x + (size_t)wid * indim;
    float a0 = 0.f, a1 = 0.f;
    for (int k = 0; k < indim; k++) {
        float xv = xr[k];               // wave-uniform
        a0 += xv * W[k * HID + lane];
        a1 += xv * W[k * HID + lane + 64];
    }
    z[(size_t)wid * HID + lane] = f2b(a0);
    z[(size_t)wid * HID + lane + 64] = f2b(a1);
    float ps = a0 * as_[lane] + a1 * as_[lane + 64];
    float pd = a0 * ad_[lane] + a1 * ad_[lane + 64];
#pragma unroll
    for (int off = 32; off > 0; off >>= 1) {
        ps += __shfl_down(ps, off);
        pd += __shfl_down(pd, off);
    }
    if (lane == 0) { es[wid] = ps; ed[wid] = pd; }
}

// ---------------- Layer 1 feature: z = h @ W1 via MFMA + fused es/ed ----------------
// One wave = 16 nodes x 128 cols. A direct from global (16B/lane), B from packed frags (hi+lo).

__global__ __launch_bounds__(256) void k_feat1(const bf16* __restrict__ h,
                        const short* __restrict__ Wf,
                        const float* __restrict__ as_, const float* __restrict__ ad_,
                        bf16* __restrict__ z, float* __restrict__ es, float* __restrict__ ed,
                        int n) {
    __shared__ __align__(16) short ztile[4][16][136];   // +8 pad: 16B row align, 4-way max on writes
    int wv = threadIdx.x >> 6, lane = threadIdx.x & 63;
    int node0 = (blockIdx.x * 4 + wv) * 16;
    if (node0 >= n) return;                 // no block barriers below (same-wave LDS only)
    int m = lane & 15, q = lane >> 4;
    const short* hrow = (const short*)h + (size_t)(node0 + m) * HID + q * 8;
    s8v af[4];
#pragma unroll
    for (int kb = 0; kb < 4; kb++) af[kb] = *(const s8v*)(hrow + kb * 32);
    f4v acc[8];
#pragma unroll
    for (int cb = 0; cb < 8; cb++) acc[cb] = (f4v){0.f, 0.f, 0.f, 0.f};
    const s8v* wf = (const s8v*)Wf;         // [2][4][8][64] frags
#pragma unroll
    for (int kb = 0; kb < 4; kb++) {
#pragma unroll
        for (int cb = 0; cb < 8; cb++) {
            acc[cb] = __builtin_amdgcn_mfma_f32_16x16x32_bf16(af[kb], wf[(kb * 8 + cb) * 64 + lane], acc[cb], 0, 0, 0);
            acc[cb] = __builtin_amdgcn_mfma_f32_16x16x32_bf16(af[kb], wf[2048 + (kb * 8 + cb) * 64 + lane], acc[cb], 0, 0, 0);
        }
    }
    // fused es/ed: C-layout row=q*4+r, col=cb*16+m
    float pe[4] = {0.f, 0.f, 0.f, 0.f}, pd[4] = {0.f, 0.f, 0.f, 0.f};
#pragma unroll
    for (int cb = 0; cb < 8; cb++) {
        float asv = as_[cb * 16 + m];
        float adv = ad_[cb * 16 + m];
#pragma unroll
        for (int r = 0; r < 4; r++) { pe[r] += acc[cb][r] * asv; pd[r] += acc[cb][r] * adv; }
    }
#pragma unroll
    for (int r = 0; r < 4; r++) {
#pragma unroll
        for (int off = 1; off < 16; off <<= 1) {
            pe[r] += __shfl_xor(pe[r], off);
            pd[r] += __shfl_xor(pd[r], off);
        }
    }
    if (m == 0) {
#pragma unroll
        for (int r = 0; r < 4; r++) {
            es[node0 + q * 4 + r] = pe[r];
            ed[node0 + q * 4 + r] = pd[r];
        }
    }
    // z store via per-wave LDS repack (same-wave RAW; compiler orders LDS ops)
#pragma unroll
    for (int cb = 0; cb < 8; cb++)
#pragma unroll
        for (int r = 0; r < 4; r++)
            ztile[wv][q * 4 + r][cb * 16 + m] = bfbits(acc[cb][r]);
#pragma unroll
    for (int i = 0; i < 4; i++) {
        int idx = i * 64 + lane;
        int row = idx >> 4, t = idx & 15;
        s8v v = *(const s8v*)&ztile[wv][row][t * 8];
        *(s8v*)((short*)z + (size_t)(node0 + row) * HID + t * 8) = v;
    }
}

// ---------------- Attention aggregation (bf16 z; per-wave LDS logit cache) ----------------

__global__ __launch_bounds__(256) void k_agg(const bf16* __restrict__ z,
                      const int* __restrict__ rowptr, const int* __restrict__ col,
                      const float* __restrict__ es, const float* __restrict__ ed,
                      const float* __restrict__ bias, bf16* __restrict__ hout, int n) {
    __shared__ float acache[4][ECAP];
    __shared__ int scache[4][ECAP];
    int wv = threadIdx.x >> 6;
    int lane = threadIdx.x & 63;
    int wid = blockIdx.x * 4 + wv;
    if (wid >= n) return;
    int d = wid;
    int s0 = rowptr[d], s1 = rowptr[d + 1];
    float edv = ed[d];
    float aself = es[d] + edv;
    aself = aself > 0.f ? aself : NEG * aself;
    float m = aself;
    for (int e = s0 + lane; e < s1; e += 64) {
        int s = col[e];
        float a = es[s] + edv;
        a = a > 0.f ? a : NEG * a;
        int q = e - s0;
        if (q < ECAP) { acache[wv][q] = a; scache[wv][q] = s; }
        m = fmaxf(m, a);
    }
#pragma unroll
    for (int off = 32; off > 0; off >>= 1) m = fmaxf(m, __shfl_xor(m, off));
    int g = lane >> 4, t = lane & 15;
    const uint4* zr = (const uint4*)z;
    float acc[8];
#pragma unroll
    for (int j = 0; j < 8; j++) acc[j] = 0.f;
    float den = 0.f;
    for (int e0 = s0; e0 < s1; e0 += 4) {
        int e = e0 + g;
        bool ok = (e < s1);
        int ee = ok ? e : s1 - 1;
        int q = ee - s0;
        int s; float a;
        if (q < ECAP) { s = scache[wv][q]; a = acache[wv][q]; }
        else { s = col[ee]; a = es[s] + edv; a = a > 0.f ? a : NEG * a; }
        float p = ok ? __expf(a - m) : 0.f;
        den += p;
        uint4 raw = zr[(size_t)s * 16 + t];
        acc[0] += p * lo_bf(raw.x); acc[1] += p * hi_bf(raw.x);
        acc[2] += p * lo_bf(raw.y); acc[3] += p * hi_bf(raw.y);
        acc[4] += p * lo_bf(raw.z); acc[5] += p * hi_bf(raw.z);
        acc[6] += p * lo_bf(raw.w); acc[7] += p * hi_bf(raw.w);
    }
#pragma unroll
    for (int off = 16; off <= 32; off <<= 1) {
        den += __shfl_xor(den, off);
#pragma unroll
        for (int j = 0; j < 8; j++) acc[j] += __shfl_xor(acc[j], off);
    }
    if (g == 0) {
        float pself = __expf(aself - m);
        den += pself;
        uint4 raw = zr[(size_t)d * 16 + t];
        acc[0] += pself * lo_bf(raw.x); acc[1] += pself * hi_bf(raw.x);
        acc[2] += pself * lo_bf(raw.y); acc[3] += pself * hi_bf(raw.y);
        acc[4] += pself * lo_bf(raw.z); acc[5] += pself * hi_bf(raw.z);
        acc[6] += pself * lo_bf(raw.w); acc[7] += pself * hi_bf(raw.w);
        float inv = 1.f / den;
        union { bf16 hv[8]; uint4 v; } uo;
#pragma unroll
        for (int j = 0; j < 8; j++) {
            float o = acc[j] * inv + bias[t * 8 + j];
            o = o > 0.f ? o : (__expf(o) - 1.f);
            uo.hv[j] = f2b(o);
        }
        ((uint4*)hout)[(size_t)d * 16 + t] = uo.v;
    }
}

// ---------------- Actor MLP + softmax via MFMA: one wave per group of 16 candidates ----------------

__global__ __launch_bounds__(256) void k_group(const bf16* __restrict__ h,
                        const int* __restrict__ cand,
                        const short* __restrict__ Wf, const float* __restrict__ mb0,
                        const float* __restrict__ mW1, const float* __restrict__ mb1,
                        float* __restrict__ out) {
    __shared__ float sc[4][16];
    int wv = threadIdx.x >> 6, lane = threadIdx.x & 63;
    int g = blockIdx.x * 4 + wv;           // ngroups % 4 == 0
    int m = lane & 15, q = lane >> 4;
    int node = cand[g * 16 + m];
    const short* hrow = (const short*)h + (size_t)node * HID + q * 8;
    s8v af[4];
#pragma unroll
    for (int kb = 0; kb < 4; kb++) af[kb] = *(const s8v*)(hrow + kb * 32);
    f4v acc[8];
#pragma unroll
    for (int cb = 0; cb < 8; cb++) acc[cb] = (f4v){0.f, 0.f, 0.f, 0.f};
    const s8v* wf = (const s8v*)Wf;
#pragma unroll
    for (int kb = 0; kb < 4; kb++) {
#pragma unroll
        for (int cb = 0; cb < 8; cb++) {
            acc[cb] = __builtin_amdgcn_mfma_f32_16x16x32_bf16(af[kb], wf[(kb * 8 + cb) * 64 + lane], acc[cb], 0, 0, 0);
            acc[cb] = __builtin_amdgcn_mfma_f32_16x16x32_bf16(af[kb], wf[2048 + (kb * 8 + cb) * 64 + lane], acc[cb], 0, 0, 0);
        }
    }
    // relu(y + mb0) . mW1, reduced over cols; C-layout row=q*4+r (candidate), col=cb*16+m
    float sr[4] = {0.f, 0.f, 0.f, 0.f};
#pragma unroll
    for (int cb = 0; cb < 8; cb++) {
        float b0v = mb0[cb * 16 + m];
        float w1v = mW1[cb * 16 + m];
#pragma unroll
        for (int r = 0; r < 4; r++) sr[r] += fmaxf(acc[cb][r] + b0v, 0.f) * w1v;
    }
#pragma unroll
    for (int r = 0; r < 4; r++) {
#pragma unroll
        for (int off = 1; off < 16; off <<= 1) sr[r] += __shfl_xor(sr[r], off);
    }
    float b1v = mb1[0];
    if (m == 0) {
#pragma unroll
        for (int r = 0; r < 4; r++) sc[wv][q * 4 + r] = sr[r] + b1v;
    }
    // softmax over the 16 scores (same-wave LDS RAW)
    if (lane < 16) {
        float s = sc[wv][lane];
        float mx = s;
#pragma unroll
        for (int off = 1; off < 16; off <<= 1) mx = fmaxf(mx, __shfl_xor(mx, off));
        float e = __expf(s - mx);
        float den = e;
#pragma unroll
        for (int off = 1; off < 16; off <<= 1) den += __shfl_xor(den, off);
        out[g * 16 + lane] = e / den;
    }
}

// ---------------- launch ----------------

extern "C" void kernel_launch(void* const* d_in, const int* in_sizes, int n_in,
                              void* d_out, int out_size, void* d_ws, size_t ws_size,
                              hipStream_t stream) {
    const int N = N_NODES;
    const float* state = (const float*)d_in[0];
    const int* ei   = (const int*)d_in[1];
    const int* cand = (const int*)d_in[2];
    const float* W0  = (const float*)d_in[3];
    const float* as0 = (const float*)d_in[4];
    const float* ad0 = (const float*)d_in[5];
    const float* b0  = (const float*)d_in[6];
    const float* W1  = (const float*)d_in[7];
    const float* as1 = (const float*)d_in[8];
    const float* ad1 = (const float*)d_in[9];
    const float* b1  = (const float*)d_in[10];
    const float* mW0 = (const float*)d_in[11];
    const float* mb0 = (const float*)d_in[12];
    const float* mW1 = (const float*)d_in[13];
    const float* mb1 = (const float*)d_in[14];

    int E = in_sizes[1] / 2;
    int M = 2 * E;                    // symmetrized; self-loops inline in k_agg
    int ncand = in_sizes[2];          // 65536
    int ngroups = ncand / 16;         // 4096
    int indim = in_sizes[0] / N;

    // workspace (~59.5 MB); pairs overlays zb (dead until k_feat0)
    char* p = (char*)d_ws;
    bf16* zb = (bf16*)p;              p += (size_t)N * HID * 2;   // 25.6 MB
    bf16* hb = (bf16*)p;              p += (size_t)N * HID * 2;   // 25.6 MB
    float* es = (float*)p;            p += (size_t)N * 4;
    float* ed = (float*)p;            p += (size_t)N * 4;
    p = (char*)(((uintptr_t)p + 15) & ~(uintptr_t)15);
    short* W1frag  = (short*)p;       p += 32768 * 2;             // 64 KB (hi+lo)
    short* mW0frag = (short*)p;       p += 32768 * 2;             // 64 KB
    int* rowptr = (int*)p;            p += (size_t)(N + 1) * 4;
    int* col    = (int*)p;            p += (size_t)M * 4;         // 6.4 MB
    int* bcnt   = (int*)p;            p += (NBUCK + 1) * 4;
    int* bbase  = (int*)p;            p += (NBUCK + 1) * 4;
    int* bnext  = (int*)p;            p += NBUCK * 4;
    int2* pairs = (int2*)zb;          // 12.8 MB overlay

    int nwb = N / 4;                  // one-wave-per-node kernels, 256 thr

    // ---- weight packing (independent) ----
    k_pack<<<64, 256, 0, stream>>>(W1, W1frag);
    k_pack<<<64, 256, 0, stream>>>(mW0, mW0frag);

    // ---- CSR build (bucketed counting sort) ----
    k_zero_int<<<1, 256, 0, stream>>>(bcnt, NBUCK);
    k_bhist<<<512, 256, 0, stream>>>(ei, E, bcnt);
    k_bscan<<<1, NBUCK, 0, stream>>>(bcnt, bbase, bnext);
    k_bscatter<<<(E + SCH - 1) / SCH, 256, 0, stream>>>(ei, E, bnext, pairs);
    k_bbuild<<<NBUCK, 256, 0, stream>>>(pairs, bbase, rowptr, col, N);

    // ---- GAT layer 0 ----
    k_feat0<<<nwb, 256, 0, stream>>>(state, W0, as0, ad0, zb, es, ed, N, indim);
    k_agg<<<nwb, 256, 0, stream>>>(zb, rowptr, col, es, ed, b0, hb, N);

    // ---- GAT layer 1 (MFMA feature GEMM + fused es/ed) ----
    int nfw = N / 16;                 // 6250 waves
    k_feat1<<<(nfw + 3) / 4, 256, 0, stream>>>(hb, W1frag, as1, ad1, zb, es, ed, N);
    k_agg<<<nwb, 256, 0, stream>>>(zb, rowptr, col, es, ed, b1, hb, N);

    // ---- actor MLP + softmax via MFMA ----
    k_group<<<ngroups / 4, 256, 0, stream>>>(hb, cand, mW0frag, mb0, mW1, mb1, (float*)d_out);
}

// Round 12
// 345.531 us; speedup vs baseline: 1.8564x; 1.1333x over previous
//
#include <hip/hip_runtime.h>
#include <hip/hip_bf16.h>
#include <math.h>
#include <stdint.h>

typedef __hip_bfloat16 bf16;
typedef __attribute__((ext_vector_type(8))) short s8v;   // 8 bf16 = 4 VGPR (MFMA A/B frag)
typedef __attribute__((ext_vector_type(4))) float f4v;   // MFMA C/D frag

#define N_NODES 100000
#define HID 128
#define NEG 0.2f
#define NBUCK 256
#define BSHIFT 9          // 512 nodes per bucket
#define ECAP 96           // per-wave LDS edge cache (mean deg 16)
#define INDIM 18

__device__ __forceinline__ float b2f(bf16 x) { return __bfloat162float(x); }
__device__ __forceinline__ bf16 f2b(float x) { return __float2bfloat16(x); }
__device__ __forceinline__ float lo_bf(unsigned int u) {
    union { unsigned int i; float f; } c; c.i = u << 16; return c.f;
}
__device__ __forceinline__ float hi_bf(unsigned int u) {
    union { unsigned int i; float f; } c; c.i = u & 0xffff0000u; return c.f;
}
__device__ __forceinline__ short bfbits(float x) {
    union { bf16 b; short s; } u; u.b = f2b(x); return u.s;
}

// ---------------- CSR build: bucketed counting sort ----------------

__global__ void k_zero_int(int* p, int n) {
    int i = blockIdx.x * blockDim.x + threadIdx.x;
    if (i < n) p[i] = 0;
}

__global__ void k_bhist(const int* __restrict__ ei, int E, int* __restrict__ bcnt) {
    __shared__ int h[NBUCK];
    int t = threadIdx.x;
    h[t] = 0;
    __syncthreads();
    int i = blockIdx.x * blockDim.x + t;
    int stride = gridDim.x * blockDim.x;
    for (; i < E; i += stride) {
        int u = ei[i], v = ei[E + i];
        atomicAdd(&h[v >> BSHIFT], 1);
        atomicAdd(&h[u >> BSHIFT], 1);
    }
    __syncthreads();
    if (h[t]) atomicAdd(&bcnt[t], h[t]);
}

__global__ void k_bscan(const int* __restrict__ bcnt, int* __restrict__ bbase,
                        int* __restrict__ bnext) {
    __shared__ int buf[2][NBUCK];
    int t = threadIdx.x;
    int v = bcnt[t];
    buf[0][t] = v;
    __syncthreads();
    int cur = 0;
    for (int off = 1; off < NBUCK; off <<= 1) {
        int x = buf[cur][t] + ((t >= off) ? buf[cur][t - off] : 0);
        buf[cur ^ 1][t] = x;
        cur ^= 1;
        __syncthreads();
    }
    int incl = buf[cur][t];
    int excl = incl - v;
    bbase[t] = excl;
    bnext[t] = excl;
    if (t == NBUCK - 1) bbase[NBUCK] = incl;
}

#define SCH 2048
#define SK 8
__global__ __launch_bounds__(256) void k_bscatter(const int* __restrict__ ei, int E,
                                                  int* __restrict__ bnext,
                                                  int2* __restrict__ pairs) {
    __shared__ int h[NBUCK], base[NBUCK], h2[NBUCK];
    int t = threadIdx.x;
    h[t] = 0; h2[t] = 0;
    __syncthreads();
    int b0 = blockIdx.x * SCH;
    int eu[SK], ev[SK];
#pragma unroll
    for (int k = 0; k < SK; k++) {
        int i = b0 + k * 256 + t;
        if (i < E) {
            int u = ei[i], v = ei[E + i];
            eu[k] = u; ev[k] = v;
            atomicAdd(&h[v >> BSHIFT], 1);
            atomicAdd(&h[u >> BSHIFT], 1);
        } else { eu[k] = -1; ev[k] = -1; }
    }
    __syncthreads();
    if (h[t] > 0) base[t] = atomicAdd(&bnext[t], h[t]);
    __syncthreads();
#pragma unroll
    for (int k = 0; k < SK; k++) {
        if (eu[k] >= 0) {
            int u = eu[k], v = ev[k];
            int bv = v >> BSHIFT;
            pairs[base[bv] + atomicAdd(&h2[bv], 1)] = make_int2(v, u);
            int bu = u >> BSHIFT;
            pairs[base[bu] + atomicAdd(&h2[bu], 1)] = make_int2(u, v);
        }
    }
}

__global__ __launch_bounds__(256) void k_bbuild(const int2* __restrict__ pairs,
                                                const int* __restrict__ bbase,
                                                int* __restrict__ rowptr,
                                                int* __restrict__ col, int n) {
    __shared__ int deg[512];
    __shared__ int off[512];
    __shared__ int s2[2][256];
    int t = threadIdx.x;
    int b = blockIdx.x;
    int node0 = b << BSHIFT;
    deg[t] = 0; deg[t + 256] = 0;
    __syncthreads();
    int p0 = bbase[b], p1 = bbase[b + 1];
    for (int i = p0 + t; i < p1; i += 256) atomicAdd(&deg[pairs[i].x - node0], 1);
    __syncthreads();
    int a0 = deg[2 * t], a1 = deg[2 * t + 1];
    int s = a0 + a1;
    s2[0][t] = s;
    __syncthreads();
    int cur = 0;
    for (int o = 1; o < 256; o <<= 1) {
        int x = s2[cur][t] + ((t >= o) ? s2[cur][t - o] : 0);
        s2[cur ^ 1][t] = x;
        cur ^= 1;
        __syncthreads();
    }
    int excl = s2[cur][t] - s;
    off[2 * t] = excl;
    off[2 * t + 1] = excl + a0;
    __syncthreads();
    for (int j = t; j < 512; j += 256) {
        int node = node0 + j;
        if (node <= n) rowptr[node] = p0 + off[j];
    }
    deg[t] = 0; deg[t + 256] = 0;
    __syncthreads();
    for (int i = p0 + t; i < p1; i += 256) {
        int2 pr = pairs[i];
        int d = pr.x - node0;
        int ofs = atomicAdd(&deg[d], 1);
        col[p0 + off[d] + ofs] = pr.y;
    }
}

// ---------------- merged weight packing ----------------
// blocks [0,64):   W1  (128x128) -> hi at W1f[0..16383], residual at +16384
// blocks [64,128): mW0 (128x128) -> same into mW0f
// blocks [128,192): W0 (18x128)  -> B1=[wh|wl|0] at W0f[0..8191], B2=[wl|wh|0] at +8192

__device__ void pack128(const float* __restrict__ W, short* __restrict__ frag, int b) {
    int idx = b * 256 + threadIdx.x;   // 0..16383
    int j = idx & 7;
    int lane = (idx >> 3) & 63;
    int cb = (idx >> 9) & 7;
    int kb = idx >> 12;
    int k = kb * 32 + (lane >> 4) * 8 + j;
    int c = cb * 16 + (lane & 15);
    float w = W[k * HID + c];
    bf16 hi = f2b(w);
    frag[idx] = bfbits(w);
    frag[16384 + idx] = bfbits(w - b2f(hi));
}

__global__ void k_packall(const float* __restrict__ W1, const float* __restrict__ mW0,
                          const float* __restrict__ W0, short* __restrict__ W1f,
                          short* __restrict__ mW0f, short* __restrict__ W0f) {
    int b = blockIdx.x;
    if (b < 64) { pack128(W1, W1f, b); return; }
    if (b < 128) { pack128(mW0, mW0f, b - 64); return; }
    int idx = (b - 128) * 256 + threadIdx.x;  // 0..16383
    int var = idx >> 13;                      // 0=B1, 1=B2
    int r = idx & 8191;
    int j = r & 7;
    int lane = (r >> 3) & 63;
    int cb = (r >> 9) & 7;
    int kb = r >> 12;                         // 0..1
    int kp = kb * 32 + (lane >> 4) * 8 + j;   // logical K position in [0,64)
    int c = cb * 16 + (lane & 15);
    short out = 0;
    if (kp < 2 * INDIM) {
        int src = (kp < INDIM) ? kp : kp - INDIM;
        float w = W0[src * HID + c];
        bf16 hi = f2b(w);
        bool want_hi = (kp < INDIM) ^ (var == 1);   // B1: [hi|lo], B2: [lo|hi]
        out = want_hi ? bfbits(w) : bfbits(w - b2f(hi));
    }
    W0f[var * 8192 + r] = out;
}

// ---------------- Layer 0 via MFMA: z = x @ W0 (bf16 out) + fused es/ed ----------------
// One wave = 16 nodes x 128 cols. A built DIRECTLY in registers (no LDS staging):
// lane (q,m) needs A[m][k] for k = kb*32 + q*8 + j only -> load from its own x row.
// Logical K layout: [xh(18) | xl(18) | 0...]; B1=[wh|wl|0], B2=[wl|wh|0];
// A*B1 + A*B2 = (xh+xl)(wh+wl) = exact fp32 product (to residual rounding).

__global__ __launch_bounds__(256) void k_feat0m(const float* __restrict__ x,
                        const short* __restrict__ Wf,
                        const float* __restrict__ as_, const float* __restrict__ ad_,
                        bf16* __restrict__ z, float* __restrict__ es, float* __restrict__ ed,
                        int n) {
    __shared__ __align__(16) short ztile[4][16][136];
    int wv = threadIdx.x >> 6, lane = threadIdx.x & 63;
    int node0 = (blockIdx.x * 4 + wv) * 16;
    if (node0 >= n) return;                 // no block barriers (same-wave LDS only)
    int m = lane & 15, q = lane >> 4;
    const float* xr = x + (size_t)(node0 + m) * INDIM;
    s8v af0, af1;
#pragma unroll
    for (int j = 0; j < 8; j++) {
        int p0 = q * 8 + j;                 // [0,32)
        float v0 = 0.f;
        if (p0 < INDIM) v0 = xr[p0];
        else if (p0 < 2 * INDIM) v0 = xr[p0 - INDIM];
        short o0;
        if (p0 < INDIM) o0 = bfbits(v0);                      // hi
        else o0 = bfbits(v0 - b2f(f2b(v0)));                  // residual
        af0[j] = o0;
        int p1 = 32 + q * 8 + j;            // [32,64); always >= 18 -> residual or 0
        float v1 = (p1 < 2 * INDIM) ? xr[p1 - INDIM] : 0.f;
        af1[j] = bfbits(v1 - b2f(f2b(v1)));
    }
    f4v acc[8];
#pragma unroll
    for (int cb = 0; cb < 8; cb++) acc[cb] = (f4v){0.f, 0.f, 0.f, 0.f};
    const s8v* wf = (const s8v*)Wf;          // [2 var][2 kb][8 cb][64 lane]
#pragma unroll
    for (int cb = 0; cb < 8; cb++) {
        acc[cb] = __builtin_amdgcn_mfma_f32_16x16x32_bf16(af0, wf[cb * 64 + lane], acc[cb], 0, 0, 0);
        acc[cb] = __builtin_amdgcn_mfma_f32_16x16x32_bf16(af1, wf[(8 + cb) * 64 + lane], acc[cb], 0, 0, 0);
        acc[cb] = __builtin_amdgcn_mfma_f32_16x16x32_bf16(af0, wf[1024 + cb * 64 + lane], acc[cb], 0, 0, 0);
        acc[cb] = __builtin_amdgcn_mfma_f32_16x16x32_bf16(af1, wf[1024 + (8 + cb) * 64 + lane], acc[cb], 0, 0, 0);
    }
    // fused es/ed: C-layout row=q*4+r, col=cb*16+m
    float pe[4] = {0.f, 0.f, 0.f, 0.f}, pd[4] = {0.f, 0.f, 0.f, 0.f};
#pragma unroll
    for (int cb = 0; cb < 8; cb++) {
        float asv = as_[cb * 16 + m];
        float adv = ad_[cb * 16 + m];
#pragma unroll
        for (int r = 0; r < 4; r++) { pe[r] += acc[cb][r] * asv; pd[r] += acc[cb][r] * adv; }
    }
#pragma unroll
    for (int r = 0; r < 4; r++) {
#pragma unroll
        for (int off = 1; off < 16; off <<= 1) {
            pe[r] += __shfl_xor(pe[r], off);
            pd[r] += __shfl_xor(pd[r], off);
        }
    }
    if (m == 0) {
#pragma unroll
        for (int r = 0; r < 4; r++) {
            es[node0 + q * 4 + r] = pe[r];
            ed[node0 + q * 4 + r] = pd[r];
        }
    }
#pragma unroll
    for (int cb = 0; cb < 8; cb++)
#pragma unroll
        for (int r = 0; r < 4; r++)
            ztile[wv][q * 4 + r][cb * 16 + m] = bfbits(acc[cb][r]);
#pragma unroll
    for (int i = 0; i < 4; i++) {
        int idx = i * 64 + lane;
        int row = idx >> 4, t = idx & 15;
        s8v v = *(const s8v*)&ztile[wv][row][t * 8];
        *(s8v*)((short*)z + (size_t)(node0 + row) * HID + t * 8) = v;
    }
}

// ---------------- Layer 1 feature: z = h @ W1 via MFMA + fused es/ed ----------------

__global__ __launch_bounds__(256) void k_feat1(const bf16* __restrict__ h,
                        const short* __restrict__ Wf,
                        const float* __restrict__ as_, const float* __restrict__ ad_,
                        bf16* __restrict__ z, float* __restrict__ es, float* __restrict__ ed,
                        int n) {
    __shared__ __align__(16) short ztile[4][16][136];
    int wv = threadIdx.x >> 6, lane = threadIdx.x & 63;
    int node0 = (blockIdx.x * 4 + wv) * 16;
    if (node0 >= n) return;
    int m = lane & 15, q = lane >> 4;
    const short* hrow = (const short*)h + (size_t)(node0 + m) * HID + q * 8;
    s8v af[4];
#pragma unroll
    for (int kb = 0; kb < 4; kb++) af[kb] = *(const s8v*)(hrow + kb * 32);
    f4v acc[8];
#pragma unroll
    for (int cb = 0; cb < 8; cb++) acc[cb] = (f4v){0.f, 0.f, 0.f, 0.f};
    const s8v* wf = (const s8v*)Wf;
#pragma unroll
    for (int kb = 0; kb < 4; kb++) {
#pragma unroll
        for (int cb = 0; cb < 8; cb++) {
            acc[cb] = __builtin_amdgcn_mfma_f32_16x16x32_bf16(af[kb], wf[(kb * 8 + cb) * 64 + lane], acc[cb], 0, 0, 0);
            acc[cb] = __builtin_amdgcn_mfma_f32_16x16x32_bf16(af[kb], wf[2048 + (kb * 8 + cb) * 64 + lane], acc[cb], 0, 0, 0);
        }
    }
    float pe[4] = {0.f, 0.f, 0.f, 0.f}, pd[4] = {0.f, 0.f, 0.f, 0.f};
#pragma unroll
    for (int cb = 0; cb < 8; cb++) {
        float asv = as_[cb * 16 + m];
        float adv = ad_[cb * 16 + m];
#pragma unroll
        for (int r = 0; r < 4; r++) { pe[r] += acc[cb][r] * asv; pd[r] += acc[cb][r] * adv; }
    }
#pragma unroll
    for (int r = 0; r < 4; r++) {
#pragma unroll
        for (int off = 1; off < 16; off <<= 1) {
            pe[r] += __shfl_xor(pe[r], off);
            pd[r] += __shfl_xor(pd[r], off);
        }
    }
    if (m == 0) {
#pragma unroll
        for (int r = 0; r < 4; r++) {
            es[node0 + q * 4 + r] = pe[r];
            ed[node0 + q * 4 + r] = pd[r];
        }
    }
#pragma unroll
    for (int cb = 0; cb < 8; cb++)
#pragma unroll
        for (int r = 0; r < 4; r++)
            ztile[wv][q * 4 + r][cb * 16 + m] = bfbits(acc[cb][r]);
#pragma unroll
    for (int i = 0; i < 4; i++) {
        int idx = i * 64 + lane;
        int row = idx >> 4, t = idx & 15;
        s8v v = *(const s8v*)&ztile[wv][row][t * 8];
        *(s8v*)((short*)z + (size_t)(node0 + row) * HID + t * 8) = v;
    }
}

// ---------------- Attention aggregation (bf16 z; per-wave LDS logit cache) ----------------

__global__ __launch_bounds__(256) void k_agg(const bf16* __restrict__ z,
                      const int* __restrict__ rowptr, const int* __restrict__ col,
                      const float* __restrict__ es, const float* __restrict__ ed,
                      const float* __restrict__ bias, bf16* __restrict__ hout, int n) {
    __shared__ float acache[4][ECAP];
    __shared__ int scache[4][ECAP];
    int wv = threadIdx.x >> 6;
    int lane = threadIdx.x & 63;
    int wid = blockIdx.x * 4 + wv;
    if (wid >= n) return;
    int d = wid;
    int s0 = rowptr[d], s1 = rowptr[d + 1];
    float edv = ed[d];
    float aself = es[d] + edv;
    aself = aself > 0.f ? aself : NEG * aself;
    float m = aself;
    for (int e = s0 + lane; e < s1; e += 64) {
        int s = col[e];
        float a = es[s] + edv;
        a = a > 0.f ? a : NEG * a;
        int q = e - s0;
        if (q < ECAP) { acache[wv][q] = a; scache[wv][q] = s; }
        m = fmaxf(m, a);
    }
#pragma unroll
    for (int off = 32; off > 0; off >>= 1) m = fmaxf(m, __shfl_xor(m, off));
    int g = lane >> 4, t = lane & 15;
    const uint4* zr = (const uint4*)z;
    float acc[8];
#pragma unroll
    for (int j = 0; j < 8; j++) acc[j] = 0.f;
    float den = 0.f;
    for (int e0 = s0; e0 < s1; e0 += 4) {
        int e = e0 + g;
        bool ok = (e < s1);
        int ee = ok ? e : s1 - 1;
        int q = ee - s0;
        int s; float a;
        if (q < ECAP) { s = scache[wv][q]; a = acache[wv][q]; }
        else { s = col[ee]; a = es[s] + edv; a = a > 0.f ? a : NEG * a; }
        float p = ok ? __expf(a - m) : 0.f;
        den += p;
        uint4 raw = zr[(size_t)s * 16 + t];
        acc[0] += p * lo_bf(raw.x); acc[1] += p * hi_bf(raw.x);
        acc[2] += p * lo_bf(raw.y); acc[3] += p * hi_bf(raw.y);
        acc[4] += p * lo_bf(raw.z); acc[5] += p * hi_bf(raw.z);
        acc[6] += p * lo_bf(raw.w); acc[7] += p * hi_bf(raw.w);
    }
#pragma unroll
    for (int off = 16; off <= 32; off <<= 1) {
        den += __shfl_xor(den, off);
#pragma unroll
        for (int j = 0; j < 8; j++) acc[j] += __shfl_xor(acc[j], off);
    }
    if (g == 0) {
        float pself = __expf(aself - m);
        den += pself;
        uint4 raw = zr[(size_t)d * 16 + t];
        acc[0] += pself * lo_bf(raw.x); acc[1] += pself * hi_bf(raw.x);
        acc[2] += pself * lo_bf(raw.y); acc[3] += pself * hi_bf(raw.y);
        acc[4] += pself * lo_bf(raw.z); acc[5] += pself * hi_bf(raw.z);
        acc[6] += pself * lo_bf(raw.w); acc[7] += pself * hi_bf(raw.w);
        float inv = 1.f / den;
        union { bf16 hv[8]; uint4 v; } uo;
#pragma unroll
        for (int j = 0; j < 8; j++) {
            float o = acc[j] * inv + bias[t * 8 + j];
            o = o > 0.f ? o : (__expf(o) - 1.f);
            uo.hv[j] = f2b(o);
        }
        ((uint4*)hout)[(size_t)d * 16 + t] = uo.v;
    }
}

// ---------------- Actor MLP + softmax via MFMA: one wave per group of 16 candidates ----------------

__global__ __launch_bounds__(256) void k_group(const bf16* __restrict__ h,
                        const int* __restrict__ cand,
                        const short* __restrict__ Wf, const float* __restrict__ mb0,
                        const float* __restrict__ mW1, const float* __restrict__ mb1,
                        float* __restrict__ out) {
    __shared__ float sc[4][16];
    int wv = threadIdx.x >> 6, lane = threadIdx.x & 63;
    int g = blockIdx.x * 4 + wv;
    int m = lane & 15, q = lane >> 4;
    int node = cand[g * 16 + m];
    const short* hrow = (const short*)h + (size_t)node * HID + q * 8;
    s8v af[4];
#pragma unroll
    for (int kb = 0; kb < 4; kb++) af[kb] = *(const s8v*)(hrow + kb * 32);
    f4v acc[8];
#pragma unroll
    for (int cb = 0; cb < 8; cb++) acc[cb] = (f4v){0.f, 0.f, 0.f, 0.f};
    const s8v* wf = (const s8v*)Wf;
#pragma unroll
    for (int kb = 0; kb < 4; kb++) {
#pragma unroll
        for (int cb = 0; cb < 8; cb++) {
            acc[cb] = __builtin_amdgcn_mfma_f32_16x16x32_bf16(af[kb], wf[(kb * 8 + cb) * 64 + lane], acc[cb], 0, 0, 0);
            acc[cb] = __builtin_amdgcn_mfma_f32_16x16x32_bf16(af[kb], wf[2048 + (kb * 8 + cb) * 64 + lane], acc[cb], 0, 0, 0);
        }
    }
    float sr[4] = {0.f, 0.f, 0.f, 0.f};
#pragma unroll
    for (int cb = 0; cb < 8; cb++) {
        float b0v = mb0[cb * 16 + m];
        float w1v = mW1[cb * 16 + m];
#pragma unroll
        for (int r = 0; r < 4; r++) sr[r] += fmaxf(acc[cb][r] + b0v, 0.f) * w1v;
    }
#pragma unroll
    for (int r = 0; r < 4; r++) {
#pragma unroll
        for (int off = 1; off < 16; off <<= 1) sr[r] += __shfl_xor(sr[r], off);
    }
    float b1v = mb1[0];
    if (m == 0) {
#pragma unroll
        for (int r = 0; r < 4; r++) sc[wv][q * 4 + r] = sr[r] + b1v;
    }
    if (lane < 16) {
        float s = sc[wv][lane];
        float mx = s;
#pragma unroll
        for (int off = 1; off < 16; off <<= 1) mx = fmaxf(mx, __shfl_xor(mx, off));
        float e = __expf(s - mx);
        float den = e;
#pragma unroll
        for (int off = 1; off < 16; off <<= 1) den += __shfl_xor(den, off);
        out[g * 16 + lane] = e / den;
    }
}

// ---------------- launch ----------------

extern "C" void kernel_launch(void* const* d_in, const int* in_sizes, int n_in,
                              void* d_out, int out_size, void* d_ws, size_t ws_size,
                              hipStream_t stream) {
    const int N = N_NODES;
    const float* state = (const float*)d_in[0];
    const int* ei   = (const int*)d_in[1];
    const int* cand = (const int*)d_in[2];
    const float* W0  = (const float*)d_in[3];
    const float* as0 = (const float*)d_in[4];
    const float* ad0 = (const float*)d_in[5];
    const float* b0  = (const float*)d_in[6];
    const float* W1  = (const float*)d_in[7];
    const float* as1 = (const float*)d_in[8];
    const float* ad1 = (const float*)d_in[9];
    const float* b1  = (const float*)d_in[10];
    const float* mW0 = (const float*)d_in[11];
    const float* mb0 = (const float*)d_in[12];
    const float* mW1 = (const float*)d_in[13];
    const float* mb1 = (const float*)d_in[14];

    int E = in_sizes[1] / 2;
    int M = 2 * E;
    int ncand = in_sizes[2];          // 65536
    int ngroups = ncand / 16;         // 4096

    // workspace (~59.6 MB); pairs overlays zb (dead until k_feat0m)
    char* p = (char*)d_ws;
    bf16* zb = (bf16*)p;              p += (size_t)N * HID * 2;   // 25.6 MB
    bf16* hb = (bf16*)p;              p += (size_t)N * HID * 2;   // 25.6 MB
    float* es = (float*)p;            p += (size_t)N * 4;
    float* ed = (float*)p;            p += (size_t)N * 4;
    p = (char*)(((uintptr_t)p + 15) & ~(uintptr_t)15);
    short* W1frag  = (short*)p;       p += 32768 * 2;             // 64 KB (hi+lo)
    short* mW0frag = (short*)p;       p += 32768 * 2;             // 64 KB
    short* W0frag  = (short*)p;       p += 16384 * 2;             // 32 KB (B1+B2)
    int* rowptr = (int*)p;            p += (size_t)(N + 1) * 4;
    int* col    = (int*)p;            p += (size_t)M * 4;         // 6.4 MB
    int* bcnt   = (int*)p;            p += (NBUCK + 1) * 4;
    int* bbase  = (int*)p;            p += (NBUCK + 1) * 4;
    int* bnext  = (int*)p;            p += NBUCK * 4;
    int2* pairs = (int2*)zb;          // 12.8 MB overlay

    int nwb = N / 4;

    // ---- weight packing (one launch) ----
    k_packall<<<192, 256, 0, stream>>>(W1, mW0, W0, W1frag, mW0frag, W0frag);

    // ---- CSR build (bucketed counting sort) ----
    k_zero_int<<<1, 256, 0, stream>>>(bcnt, NBUCK);
    k_bhist<<<512, 256, 0, stream>>>(ei, E, bcnt);
    k_bscan<<<1, NBUCK, 0, stream>>>(bcnt, bbase, bnext);
    k_bscatter<<<(E + SCH - 1) / SCH, 256, 0, stream>>>(ei, E, bnext, pairs);
    k_bbuild<<<NBUCK, 256, 0, stream>>>(pairs, bbase, rowptr, col, N);

    // ---- GAT layer 0 (MFMA feature GEMM + fused es/ed) ----
    int nfb = (N / 16 + 3) / 4;       // 6250 waves / 4 per block
    k_feat0m<<<nfb, 256, 0, stream>>>(state, W0frag, as0, ad0, zb, es, ed, N);
    k_agg<<<nwb, 256, 0, stream>>>(zb, rowptr, col, es, ed, b0, hb, N);

    // ---- GAT layer 1 (MFMA feature GEMM + fused es/ed) ----
    k_feat1<<<nfb, 256, 0, stream>>>(hb, W1frag, as1, ad1, zb, es, ed, N);
    k_agg<<<nwb, 256, 0, stream>>>(zb, rowptr, col, es, ed, b1, hb, N);

    // ---- actor MLP + softmax via MFMA ----
    k_group<<<ngroups / 4, 256, 0, stream>>>(hb, cand, mW0frag, mb0, mW1, mb1, (float*)d_out);
}